// Round 18
// baseline (194.775 us; speedup 1.0000x reference)
//
#include <hip/hip_runtime.h>
#include <cmath>
#include <complex>

// Problem constants
constexpr int TT  = 50;            // time length
constexpr int NB  = 50;            // batch
constexpr int NC  = 4096;          // channels
constexpr int NCH = NB * NC;       // 204800 independent series
constexpr int PAD = 49;
constexpr int EXT = TT + 2 * PAD;  // 148
constexpr int CT  = 8;             // channel tile per block (block = CT x NB = 400 thr)

struct Coefs {
    double b0[2][2], b1[2][2], b2[2][2], a1[2][2], a2[2][2];
    double zi0[2][2], zi1[2][2];
};

// ---------------- Setup kernel: build the 2x50x50 filtfilt+demean matrix -----------
// Mt[(band*TT + k)*TT + t] = d y[t] / d x[k] (y demeaned over t), double precision.
// One block per band, thread j = basis column. Round-7 rewrite (verified r8-r17):
// analytic forward input (write-only forward pass), fused biquad sections
// (bit-identical dataflow), unroll-4 backward so ds_reads prefetch ahead.
__global__ void __launch_bounds__(64) build_M(float* __restrict__ Mt, Coefs cf) {
    __shared__ double e[EXT][TT];   // 148*50*8 = 59.2 KB
    const int band = blockIdx.x;
    const int j = threadIdx.x;
    if (j >= TT) return;

    const double b0a = cf.b0[band][0], b1a = cf.b1[band][0], b2a = cf.b2[band][0];
    const double a1a = cf.a1[band][0], a2a = cf.a2[band][0];
    const double b0b = cf.b0[band][1], b1b = cf.b1[band][1], b2b = cf.b2[band][1];
    const double a1b = cf.a1[band][1], a2b = cf.a2[band][1];

    // ext[0] = 2*x[0] - x[PAD]  (basis: delta at j)
    const double x0 = (j == 0 ? 2.0 : 0.0) - (j == PAD ? 1.0 : 0.0);

    double za0 = cf.zi0[band][0] * x0, za1 = cf.zi1[band][0] * x0;
    double zb0 = cf.zi0[band][1] * x0, zb1 = cf.zi1[band][1] * x0;

    double ylast = 0.0;
#pragma unroll
    for (int i = 0; i < EXT; ++i) {
        double xt;
        if (i < PAD) {                       // left odd-extension
            xt = (j == 0 ? 2.0 : 0.0) - (j == (PAD - i) ? 1.0 : 0.0);
        } else if (i < PAD + TT) {           // body: delta
            xt = (j == (i - PAD) ? 1.0 : 0.0);
        } else {                             // right odd-extension
            xt = (j == TT - 1 ? 2.0 : 0.0) - (j == (2 * TT - 2 + PAD - i) ? 1.0 : 0.0);
        }
        const double y0 = b0a * xt + za0;    // section 0
        za0 = b1a * xt + za1 - a1a * y0;
        za1 = b2a * xt - a2a * y0;
        const double y1 = b0b * y0 + zb0;    // section 1 (fused, in-register)
        zb0 = b1b * y0 + zb1 - a1b * y1;
        zb1 = b2b * y0 - a2b * y1;
        e[i][j] = y1;                        // write-only: no LDS read in this pass
        ylast = y1;
    }

    // backward pass over the reversed sequence; zi scaled by its first sample = ylast
    za0 = cf.zi0[band][0] * ylast; za1 = cf.zi1[band][0] * ylast;
    zb0 = cf.zi0[band][1] * ylast; zb1 = cf.zi1[band][1] * ylast;
#pragma unroll 4
    for (int m = 0; m < EXT; ++m) {
        const int i = EXT - 1 - m;
        const double xt = e[i][j];           // independent addr -> prefetches under unroll
        const double y0 = b0a * xt + za0;
        za0 = b1a * xt + za1 - a1a * y0;
        za1 = b2a * xt - a2a * y0;
        const double y1 = b0b * y0 + zb0;
        zb0 = b1b * y0 + zb1 - a1b * y1;
        zb1 = b2b * y0 - a2b * y1;
        e[i][j] = y1;
    }

    // slice [PAD, PAD+TT) and fold the demean over t (ascending -- verified order)
    double mean = 0.0;
#pragma unroll
    for (int t = 0; t < TT; ++t) mean += e[PAD + t][j];
    mean *= (1.0 / TT);
#pragma unroll
    for (int t = 0; t < TT; ++t)
        Mt[(band * TT + j) * TT + t] = (float)(e[PAD + t][j] - mean);
}

// ---------------- Fused GEMV + stats + normalize, one block = (CT ch) x (all NB b) --
// Verified r16/r17 @ CT=16: 58-60us, absmax=8, WRITE exactly ideal, VGPR=36.
// ROUND-17 POST-MORTEM (both predicted deltas failed -> theory updated):
//  (1) Occupancy stuck at 28% (1 block/CU) under BOTH (1,4) and (1,7): the blocker
//      is the 800-THREAD BLOCK GRANULARITY (a 12.5-wave monolith doesn't co-schedule),
//      not the waves/EU cap. Fix: CT=8 -> 400-thread (6.25-wave) blocks -> scheduler
//      can pack 4-5 blocks/CU (25-31 waves). The quirk needs all NB=50 batches
//      in-block (stats indexed by batch row t) -- CT is the free dimension, NB is not.
//  (2) FETCH stuck at 80MB (2x x): band-adjacent blocks round-robin to DIFFERENT
//      XCDs (private L2s), so dispatch adjacency can't share x. Re-read is L3-served
//      (~6us); dropped as a goal.
// waves_per_eu(1,8): budget 512/8 = 64 >= measured 36 VGPR (f[50] AGPR-resident).
// Watch-item: wave now = 8 batches x 8 ch -> 32B store segments; relies on L2 merging
// with co-resident neighbor tiles. WRITE_SIZE is the verdict (>90MB -> revert CT=16).
// Numerics byte-identical to r16/r17: same fmaf chains (k asc, t asc), same mu/ss
// order, same LDS-quirk epilogue.
__global__ __launch_bounds__(CT * NB) __attribute__((amdgpu_waves_per_eu(1, 8)))
void fused_bn(const float* __restrict__ x, const float* __restrict__ Mt,
              float* __restrict__ out) {
    const int tx   = threadIdx.x;               // channel within tile
    const int b    = threadIdx.y;               // batch
    const int band = blockIdx.x;                // band-fastest (neutral, kept)
    const int c    = blockIdx.y * CT + tx;
    const int i    = b * NC + c;                // column index into [B,C] plane

    __shared__ float sm_mu [NB][CT];
    __shared__ float sm_inv[NB][CT];

    const float* __restrict__ Mb   = Mt + band * (TT * TT);
    const float* __restrict__ xcol = x + i;

    float f[TT];
#pragma unroll
    for (int t = 0; t < TT; ++t) f[t] = 0.f;

    // unroll-5 groups: 5 independent x loads hoist to the top of each group; M rows
    // are wave-uniform -> s_load broadcast (no VGPR cost). Verified chain order.
#pragma unroll 5
    for (int k = 0; k < TT; ++k) {
        const float xk = xcol[(size_t)k * NCH];
        const float* __restrict__ r = Mb + k * TT;
#pragma unroll
        for (int t = 0; t < TT; ++t) f[t] = fmaf(r[t], xk, f[t]);
    }

    // ddof=1 std about the actual mean (matches np.std); same op order as verified.
    float mu = 0.f;
#pragma unroll
    for (int t = 0; t < TT; ++t) mu += f[t];
    mu *= (1.0f / TT);
    float ss = 0.f;
#pragma unroll
    for (int t = 0; t < TT; ++t) {
        const float h = f[t] - mu;
        ss = fmaf(h, h, ss);
    }
    const float inv = 1.0f / sqrtf(ss * (1.0f / (TT - 1)));

    sm_mu [b][tx] = mu;
    sm_inv[b][tx] = inv;
    __syncthreads();   // all stats of this (band, c-tile) visible block-wide

    // normalize in-register f with row-t stats (THE QUIRK) and store out
    float* __restrict__ ob = out + (size_t)band * TT * NCH;
#pragma unroll
    for (int t = 0; t < TT; ++t) {
        const float v = (f[t] - sm_mu[t][tx]) * sm_inv[t][tx];
        ob[(size_t)t * NCH + i] = v;
    }
}

// ---------------- Host: Butterworth bandpass SOS + zi (reference-exact, double) ----
static Coefs make_coefs() {
    Coefs cf;
    const double bands[2][2] = {{0.05, 0.15}, {0.2, 0.4}};
    const int n = 2;  // ORDER
    for (int bd = 0; bd < 2; ++bd) {
        const double fs = 2.0;
        const double w1 = bands[bd][0], w2 = bands[bd][1];
        const double warped0 = 2.0 * fs * std::tan(M_PI * w1 / fs);
        const double warped1 = 2.0 * fs * std::tan(M_PI * w2 / fs);
        const double bw = warped1 - warped0;
        const double wo = std::sqrt(warped0 * warped1);
        std::complex<double> p_bp[4];
        for (int k = 1; k <= n; ++k) {
            std::complex<double> p = -std::exp(std::complex<double>(0.0, M_PI * (2 * k - 1) / (2.0 * n)));
            std::complex<double> plp = p * (bw / 2.0);
            std::complex<double> disc = std::sqrt(plp * plp - std::complex<double>(wo * wo, 0.0));
            p_bp[k - 1] = plp + disc;
            p_bp[n + k - 1] = plp - disc;
        }
        const double fs2 = 2.0 * fs;
        std::complex<double> prod(1.0, 0.0);
        for (int i = 0; i < 2 * n; ++i) prod *= (fs2 - p_bp[i]);
        const double gain = std::pow(bw, n) * std::pow(fs2, n) / prod.real();
        std::complex<double> p_d[4];
        for (int i = 0; i < 2 * n; ++i) p_d[i] = (fs2 + p_bp[i]) / (fs2 - p_bp[i]);
        double sos[2][6];
        int cnt = 0;
        for (int i = 0; i < 2 * n; ++i) {
            if (p_d[i].imag() > 0) {
                const double g = (cnt == 0) ? gain : 1.0;
                sos[cnt][0] = g;
                sos[cnt][1] = 0.0;
                sos[cnt][2] = -g;
                sos[cnt][3] = 1.0;
                sos[cnt][4] = -2.0 * p_d[i].real();
                sos[cnt][5] = std::norm(p_d[i]);
                ++cnt;
            }
        }
        double scale = 1.0;
        for (int s = 0; s < 2; ++s) {
            const double b0 = sos[s][0], b1 = sos[s][1], b2 = sos[s][2];
            const double a1 = sos[s][4], a2 = sos[s][5];
            const double B0 = b1 - a1 * b0, B1 = b2 - a2 * b0;
            const double det = 1.0 + a1 + a2;
            cf.b0[bd][s] = b0; cf.b1[bd][s] = b1; cf.b2[bd][s] = b2;
            cf.a1[bd][s] = a1; cf.a2[bd][s] = a2;
            cf.zi0[bd][s] = scale * (B0 + B1) / det;
            cf.zi1[bd][s] = scale * ((1.0 + a1) * B1 - a2 * B0) / det;
            scale *= (b0 + b1 + b2) / (1.0 + a1 + a2);
        }
    }
    return cf;
}

extern "C" void kernel_launch(void* const* d_in, const int* in_sizes, int n_in,
                              void* d_out, int out_size, void* d_ws, size_t ws_size,
                              hipStream_t stream) {
    const float* x = (const float*)d_in[0];
    float* out = (float*)d_out;
    float* Mt = (float*)d_ws;  // 2*50*50 floats = 20 KB

    const Coefs cf = make_coefs();
    build_M<<<dim3(2), dim3(64), 0, stream>>>(Mt, cf);
    fused_bn<<<dim3(2, NC / CT), dim3(CT, NB), 0, stream>>>(x, Mt, out);
}